// Round 2
// baseline (158.266 us; speedup 1.0000x reference)
//
#include <hip/hip_runtime.h>

// EdgeFeatureEncoding: proj = edge_attr @ W + b  (E x 8), scatter-add into
// dense (N, N, 8) bias at (i, j) with validity mask.
//
// Phase 1: custom float4 grid-stride zero-fill (rocclr's fillBufferAligned ran
//          at only 1.69 TB/s for this 512 MiB memset; same-session 2 GiB fills
//          hit 6.7 TB/s, so we use their proven config: 2048x256, coalesced).
// Phase 2: scatter kernel — 16 lanes per edge, coalesced float4 row loads,
//          W rows held in registers, shfl_xor group reduction, 8 fp32 atomics
//          per edge (lanes 0..7 of each 16-lane group).

__global__ __launch_bounds__(256) void efe_fill_kernel(float4* __restrict__ out,
                                                       long n4) {
    const long stride = (long)gridDim.x * blockDim.x;
    const float4 z = make_float4(0.f, 0.f, 0.f, 0.f);
    for (long i = (long)blockIdx.x * blockDim.x + threadIdx.x; i < n4; i += stride)
        out[i] = z;
}

__global__ __launch_bounds__(256) void efe_scatter_kernel(
    const int* __restrict__ ei,      // (2, E) row-major: ei[e]=i, ei[E+e]=j
    const float* __restrict__ attr,  // (E, 128)
    const int* __restrict__ nn,      // num_nodes (1 element, device)
    const float* __restrict__ Wm,    // (128, 8)
    const float* __restrict__ bv,    // (8,)
    float* __restrict__ out,         // (N, N, 8), pre-zeroed
    int E)
{
    const int N = nn[0];
    const int tid    = blockIdx.x * blockDim.x + threadIdx.x;
    const int wave   = tid >> 6;                       // global wave id
    const int lane   = threadIdx.x & 63;
    const int lg     = lane & 15;                      // lane within 16-lane group
    const int sub    = lane >> 4;                      // edge slot within wave (0..3)
    const int nwaves = (gridDim.x * blockDim.x) >> 6;

    // Preload this lane's slice of W into registers: rows k = half*64 + lg*4 + c.
    float w[2][4][8];
#pragma unroll
    for (int half = 0; half < 2; ++half)
#pragma unroll
        for (int c = 0; c < 4; ++c) {
            const int k = half * 64 + lg * 4 + c;
#pragma unroll
            for (int h = 0; h < 8; ++h) w[half][c][h] = Wm[k * 8 + h];
        }
    float bh[8];
#pragma unroll
    for (int h = 0; h < 8; ++h) bh[h] = bv[h];

    const int nquads = (E + 3) >> 2;  // 4 edges per wave-iteration
    for (int q = wave; q < nquads; q += nwaves) {
        const int e = q * 4 + sub;
        const bool live = (e < E);

        // Prefetch indices early so the latency hides under the row loads.
        int i = 0, j = 0;
        if (live) { i = ei[e]; j = ei[E + e]; }

        float acc[8];
#pragma unroll
        for (int h = 0; h < 8; ++h) acc[h] = 0.f;

        if (live) {
            // 16 lanes x float4 = the full 128-float row, coalesced (2 KiB/wave).
            const float4* row = (const float4*)(attr + (size_t)e * 128);
#pragma unroll
            for (int half = 0; half < 2; ++half) {
                const float4 v = row[half * 16 + lg];
#pragma unroll
                for (int h = 0; h < 8; ++h)
                    acc[h] += v.x * w[half][0][h] + v.y * w[half][1][h]
                            + v.z * w[half][2][h] + v.w * w[half][3][h];
            }
        }
        // Tree-reduce each head across the 16-lane group (xor masks 1,2,4,8
        // stay within the group on wave64). Dead lanes contribute 0.
#pragma unroll
        for (int d = 1; d < 16; d <<= 1)
#pragma unroll
            for (int h = 0; h < 8; ++h)
                acc[h] += __shfl_xor(acc[h], d, 64);

        if (live && lg < 8) {
            if (i >= 0 && i < N && j >= 0 && j < N) {
                // Lane lg handles head lg: select acc[lg]+bh[lg] via an
                // unrolled cndmask chain (no runtime register indexing).
                float v = acc[0] + bh[0];
#pragma unroll
                for (int h = 1; h < 8; ++h) {
                    const float cand = acc[h] + bh[h];
                    v = (lg == h) ? cand : v;
                }
                atomicAdd(out + (((size_t)i * N + j) << 3) + lg, v);
            }
        }
    }
}

extern "C" void kernel_launch(void* const* d_in, const int* in_sizes, int n_in,
                              void* d_out, int out_size, void* d_ws, size_t ws_size,
                              hipStream_t stream) {
    const int*   ei   = (const int*)d_in[0];    // edge_index (2, E) int32
    const float* attr = (const float*)d_in[1];  // edge_attr (E, 128) f32
    const int*   nn   = (const int*)d_in[2];    // num_nodes scalar
    const float* Wm   = (const float*)d_in[3];  // W (128, 8) f32
    const float* bv   = (const float*)d_in[4];  // b (8,) f32
    float*       out  = (float*)d_out;          // (N, N, 8) f32

    const int E = in_sizes[0] / 2;

    // Output must be zeroed every call (harness poisons once, never re-poisons).
    // out_size = N*N*8, divisible by 4.
    const long n4 = (long)out_size / 4;
    efe_fill_kernel<<<2048, 256, 0, stream>>>((float4*)d_out, n4);

    // 2048 blocks x 256 threads = 8192 waves; grid-stride over E/4 = 32768
    // edge-quads (4 iterations/wave) so the register-held W amortizes.
    efe_scatter_kernel<<<2048, 256, 0, stream>>>(ei, attr, nn, Wm, bv, out, E);
}

// Round 3
// 152.889 us; speedup vs baseline: 1.0352x; 1.0352x over previous
//
#include <hip/hip_runtime.h>
#include <math.h>

// EdgeFeatureEncoding: proj = edge_attr @ W + b (E x 8), scatter-add into
// dense (N, N, 8) bias at (i, j).
//
// Fused path (default):
//   memset(counters)  ~66 KB, cheap node
//   K1 efe_proj_bin:  proj GEMM (16-lane groups, coalesced float4 reads,
//                     W in registers, shfl_xor reduce) + bin edges by output
//                     chunk (1024 cells = 32 KiB out) via atomic cursors.
//   K4 efe_fill_inject: one block per chunk; zero accumulators in registers,
//                     add this chunk's binned edge contributions, then write
//                     the whole chunk with 8 coalesced dwordx4 stores/thread.
//                     One streaming write of the 512 MiB output, NO atomics
//                     to HBM-missing lines, no separate memset of d_out.
// Fallback (ws too small / odd shapes): hipMemsetAsync(d_out) + atomic scatter.

#define CHUNK_CELLS 1024   // cells per chunk (cell = 8 floats -> 32 KiB out)
#define BIN_CAP     64     // record capacity per chunk (lambda ~= 8 here)

// ---------------------------------------------------------------- K1: proj+bin
__global__ __launch_bounds__(256) void efe_proj_bin_kernel(
    const int* __restrict__ ei,      // (2, E): ei[e]=i, ei[E+e]=j
    const float* __restrict__ attr,  // (E, 128)
    const int* __restrict__ nn,      // num_nodes (device scalar)
    const float* __restrict__ Wm,    // (128, 8)
    const float* __restrict__ bv,    // (8,)
    float* __restrict__ proj,        // ws: (E, 8)
    unsigned* __restrict__ counters, // ws: (nchunks,) zeroed per call
    unsigned* __restrict__ bins,     // ws: (nchunks, BIN_CAP) rec=(lc<<20)|e
    unsigned* __restrict__ ocnt,     // ws: overflow count (zeroed per call)
    unsigned long long* __restrict__ ovf, // ws: (E,) overflow (cell<<32)|e
    int E)
{
    const int N = nn[0];
    const int tid    = blockIdx.x * blockDim.x + threadIdx.x;
    const int wave   = tid >> 6;
    const int lane   = threadIdx.x & 63;
    const int lg     = lane & 15;
    const int sub    = lane >> 4;
    const int nwaves = (gridDim.x * blockDim.x) >> 6;

    // W slice in registers: rows k = half*64 + lg*4 + c.
    float w[2][4][8];
#pragma unroll
    for (int half = 0; half < 2; ++half)
#pragma unroll
        for (int c = 0; c < 4; ++c) {
            const int k = half * 64 + lg * 4 + c;
#pragma unroll
            for (int h = 0; h < 8; ++h) w[half][c][h] = Wm[k * 8 + h];
        }
    float bh[8];
#pragma unroll
    for (int h = 0; h < 8; ++h) bh[h] = bv[h];

    const int nquads = (E + 3) >> 2;
    for (int q = wave; q < nquads; q += nwaves) {
        const int e = q * 4 + sub;
        const bool live = (e < E);

        int i = 0, j = 0;
        if (live) { i = ei[e]; j = ei[E + e]; }

        float acc[8];
#pragma unroll
        for (int h = 0; h < 8; ++h) acc[h] = 0.f;

        if (live) {
            const float4* row = (const float4*)(attr + (size_t)e * 128);
#pragma unroll
            for (int half = 0; half < 2; ++half) {
                const float4 v = row[half * 16 + lg];
#pragma unroll
                for (int h = 0; h < 8; ++h)
                    acc[h] += v.x * w[half][0][h] + v.y * w[half][1][h]
                            + v.z * w[half][2][h] + v.w * w[half][3][h];
            }
        }
        // 16-lane group tree reduce (xor masks 1,2,4,8 stay in-group on wave64).
#pragma unroll
        for (int d = 1; d < 16; d <<= 1)
#pragma unroll
            for (int h = 0; h < 8; ++h)
                acc[h] += __shfl_xor(acc[h], d, 64);

        if (live && lg < 8) {
            float v = acc[0] + bh[0];
#pragma unroll
            for (int h = 1; h < 8; ++h) {
                const float cand = acc[h] + bh[h];
                v = (lg == h) ? cand : v;
            }
            proj[(size_t)e * 8 + lg] = v;
        }
        if (live && lg == 0) {
            if (i >= 0 && i < N && j >= 0 && j < N) {
                const long cell = (long)i * N + j;
                const unsigned chunk = (unsigned)(cell >> 10);   // /CHUNK_CELLS
                const unsigned lc    = (unsigned)(cell & 1023u);
                const unsigned pos = atomicAdd(&counters[chunk], 1u);
                if (pos < BIN_CAP)
                    bins[(size_t)chunk * BIN_CAP + pos] = (lc << 20) | (unsigned)e;
                else {
                    const unsigned op = atomicAdd(ocnt, 1u);
                    ovf[op] = ((unsigned long long)cell << 32) | (unsigned)e;
                }
            }
        }
    }
}

// ---------------------------------------------------------- K4: fill + inject
__global__ __launch_bounds__(256) void efe_fill_inject_kernel(
    const unsigned* __restrict__ counters,
    const unsigned* __restrict__ bins,
    const unsigned* __restrict__ ocnt,
    const unsigned long long* __restrict__ ovf,
    const float* __restrict__ proj,
    float* __restrict__ out)
{
    const unsigned chunk = blockIdx.x;
    const int t = threadIdx.x;

    // Thread t owns float4 slots f = k*256 + t, k=0..7 (2048 float4 / chunk).
    // Stores are unit-stride across lanes per instruction (coalesced 1KiB/wave).
    float4 acc[8];  // constant-indexed only (rule: no runtime reg indexing)
#pragma unroll
    for (int k = 0; k < 8; ++k) acc[k] = make_float4(0.f, 0.f, 0.f, 0.f);

    unsigned cnt = counters[chunk];
    if (cnt > BIN_CAP) cnt = BIN_CAP;
    const unsigned* mybins = bins + (size_t)chunk * BIN_CAP;

    for (unsigned r = 0; r < cnt; ++r) {           // uniform loop, avg ~8 iters
        const unsigned rec = mybins[r];            // broadcast load
        const int lc = (int)(rec >> 20);           // local cell 0..1023
        const unsigned e = rec & 0xFFFFFu;
        const int f0 = lc << 1, f1 = f0 | 1;       // the cell's two float4 slots
        if ((f0 & 255) == t) {
            const float4 p = *(const float4*)(proj + (size_t)e * 8);
            const int k = f0 >> 8;
#pragma unroll
            for (int kk = 0; kk < 8; ++kk)
                if (kk == k) { acc[kk].x += p.x; acc[kk].y += p.y;
                               acc[kk].z += p.z; acc[kk].w += p.w; }
        }
        if ((f1 & 255) == t) {
            const float4 p = *(const float4*)(proj + (size_t)e * 8 + 4);
            const int k = f1 >> 8;
#pragma unroll
            for (int kk = 0; kk < 8; ++kk)
                if (kk == k) { acc[kk].x += p.x; acc[kk].y += p.y;
                               acc[kk].z += p.z; acc[kk].w += p.w; }
        }
    }

    float4* out4 = (float4*)out + (size_t)chunk * (CHUNK_CELLS * 8 / 4);
#pragma unroll
    for (int k = 0; k < 8; ++k) out4[(size_t)k * 256 + t] = acc[k];

    // Overflow records (count is 0 for this input; kept for correctness).
    // Only the owning block touches its chunk, after its own stores.
    const unsigned oc = *ocnt;
    if (oc) {
        __threadfence();
        __syncthreads();
        if (t < 8) {
            for (unsigned o = 0; o < oc; ++o) {
                const unsigned long long rec = ovf[o];
                const long cell = (long)(rec >> 32);
                const unsigned e = (unsigned)(rec & 0xFFFFFFFFu);
                if ((unsigned)(cell >> 10) == chunk)
                    atomicAdd(out + (size_t)cell * 8 + t, proj[(size_t)e * 8 + t]);
            }
        }
    }
}

// ------------------------------------------------------- fallback: atomic path
__global__ __launch_bounds__(256) void efe_scatter_kernel(
    const int* __restrict__ ei, const float* __restrict__ attr,
    const int* __restrict__ nn, const float* __restrict__ Wm,
    const float* __restrict__ bv, float* __restrict__ out, int E)
{
    const int N = nn[0];
    const int tid    = blockIdx.x * blockDim.x + threadIdx.x;
    const int wave   = tid >> 6;
    const int lane   = threadIdx.x & 63;
    const int lg     = lane & 15;
    const int sub    = lane >> 4;
    const int nwaves = (gridDim.x * blockDim.x) >> 6;

    float w[2][4][8];
#pragma unroll
    for (int half = 0; half < 2; ++half)
#pragma unroll
        for (int c = 0; c < 4; ++c) {
            const int k = half * 64 + lg * 4 + c;
#pragma unroll
            for (int h = 0; h < 8; ++h) w[half][c][h] = Wm[k * 8 + h];
        }
    float bh[8];
#pragma unroll
    for (int h = 0; h < 8; ++h) bh[h] = bv[h];

    const int nquads = (E + 3) >> 2;
    for (int q = wave; q < nquads; q += nwaves) {
        const int e = q * 4 + sub;
        const bool live = (e < E);
        int i = 0, j = 0;
        if (live) { i = ei[e]; j = ei[E + e]; }
        float acc[8];
#pragma unroll
        for (int h = 0; h < 8; ++h) acc[h] = 0.f;
        if (live) {
            const float4* row = (const float4*)(attr + (size_t)e * 128);
#pragma unroll
            for (int half = 0; half < 2; ++half) {
                const float4 v = row[half * 16 + lg];
#pragma unroll
                for (int h = 0; h < 8; ++h)
                    acc[h] += v.x * w[half][0][h] + v.y * w[half][1][h]
                            + v.z * w[half][2][h] + v.w * w[half][3][h];
            }
        }
#pragma unroll
        for (int d = 1; d < 16; d <<= 1)
#pragma unroll
            for (int h = 0; h < 8; ++h)
                acc[h] += __shfl_xor(acc[h], d, 64);
        if (live && lg < 8 && i >= 0 && i < N && j >= 0 && j < N) {
            float v = acc[0] + bh[0];
#pragma unroll
            for (int h = 1; h < 8; ++h) {
                const float cand = acc[h] + bh[h];
                v = (lg == h) ? cand : v;
            }
            atomicAdd(out + (((size_t)i * N + j) << 3) + lg, v);
        }
    }
}

extern "C" void kernel_launch(void* const* d_in, const int* in_sizes, int n_in,
                              void* d_out, int out_size, void* d_ws, size_t ws_size,
                              hipStream_t stream) {
    const int*   ei   = (const int*)d_in[0];
    const float* attr = (const float*)d_in[1];
    const int*   nn   = (const int*)d_in[2];
    const float* Wm   = (const float*)d_in[3];
    const float* bv   = (const float*)d_in[4];
    float*       out  = (float*)d_out;

    const int E = in_sizes[0] / 2;

    // Host-side geometry: out_size = N*N*8 (host doesn't see num_nodes' value).
    const long ncells = (long)out_size / 8;
    const long Nh = (long)(sqrt((double)ncells) + 0.5);
    const bool shape_ok = (Nh * Nh == ncells) && (ncells % CHUNK_CELLS == 0) &&
                          (E > 0) && (E <= (1 << 20));

    // ws layout (256B-aligned regions)
    const size_t nchunks = (size_t)(ncells / CHUNK_CELLS);
    const size_t o_cnt  = 0;
    const size_t o_ocnt = nchunks * 4;
    const size_t o_ovf  = ((o_ocnt + 4 + 255) / 256) * 256;
    const size_t o_proj = ((o_ovf + (size_t)E * 8 + 255) / 256) * 256;
    const size_t o_bins = ((o_proj + (size_t)E * 32 + 255) / 256) * 256;
    const size_t need   = o_bins + nchunks * BIN_CAP * 4;

    if (shape_ok && ws_size >= need) {
        unsigned* counters = (unsigned*)((char*)d_ws + o_cnt);
        unsigned* ocnt     = (unsigned*)((char*)d_ws + o_ocnt);
        unsigned long long* ovf = (unsigned long long*)((char*)d_ws + o_ovf);
        float*    proj     = (float*)((char*)d_ws + o_proj);
        unsigned* bins     = (unsigned*)((char*)d_ws + o_bins);

        // counters + overflow count must be zero every call (ws is poisoned
        // once with 0xAA and never re-poisoned).
        hipMemsetAsync(d_ws, 0, o_ovf, stream);

        efe_proj_bin_kernel<<<2048, 256, 0, stream>>>(
            ei, attr, nn, Wm, bv, proj, counters, bins, ocnt, ovf, E);

        efe_fill_inject_kernel<<<(unsigned)nchunks, 256, 0, stream>>>(
            counters, bins, ocnt, ovf, proj, out);
    } else {
        // Fallback: memset node (proven ~6.6 TB/s) + atomic scatter.
        hipMemsetAsync(d_out, 0, (size_t)out_size * sizeof(float), stream);
        efe_scatter_kernel<<<2048, 256, 0, stream>>>(ei, attr, nn, Wm, bv, out, E);
    }
}

// Round 4
// 148.107 us; speedup vs baseline: 1.0686x; 1.0323x over previous
//
#include <hip/hip_runtime.h>
#include <math.h>

// EdgeFeatureEncoding: proj = edge_attr @ W + b (E x 8), scatter-add into
// dense (N, N, 8) bias at (i, j).
//
// Fused path:
//   K0 efe_zero_counters: zero per-chunk cursors + overflow count (own kernel;
//                         rocclr's small fillBufferAligned profiled at 0.3 GB/s).
//   K1 efe_proj_bin:      proj GEMM (16-lane groups, coalesced float4 reads,
//                         W in registers, shfl_xor reduce) + bin edges by
//                         output chunk (1024 cells = 32 KiB out).
//   K4 efe_fill_inject:   one block per chunk; 16 bin slots loaded in ONE
//                         parallel unrolled burst (no dependent-load chain),
//                         merge into register accumulators, then write the
//                         whole chunk with NONTEMPORAL dwordx4 stores (avoid
//                         L2 write-allocate RFO on the 512 MiB stream).
//   K5 efe_overflow:      rare bin-overflow records (Poisson(8) tail past 16)
//                         via atomicAdd after K4. Usually ~0 work.
// Fallback (ws too small / odd shapes): hipMemsetAsync + atomic scatter.

#define CHUNK_CELLS 1024   // cells per chunk (cell = 8 floats -> 32 KiB out)
#define BIN_CAP     16     // slots per chunk; lambda ~= 8 here, tail -> K5

typedef float f32x4 __attribute__((ext_vector_type(4)));

// ------------------------------------------------------------- K0: zero state
__global__ __launch_bounds__(256) void efe_zero_counters(unsigned* __restrict__ p,
                                                         int n) {
    const int i = blockIdx.x * blockDim.x + threadIdx.x;
    if (i < n) p[i] = 0u;
}

// ---------------------------------------------------------------- K1: proj+bin
__global__ __launch_bounds__(256) void efe_proj_bin_kernel(
    const int* __restrict__ ei,      // (2, E): ei[e]=i, ei[E+e]=j
    const float* __restrict__ attr,  // (E, 128)
    const int* __restrict__ nn,      // num_nodes (device scalar)
    const float* __restrict__ Wm,    // (128, 8)
    const float* __restrict__ bv,    // (8,)
    float* __restrict__ proj,        // ws: (E, 8)
    unsigned* __restrict__ counters, // ws: (nchunks,) zeroed by K0
    unsigned* __restrict__ bins,     // ws: (nchunks, BIN_CAP) rec=(lc<<20)|e
    unsigned* __restrict__ ocnt,     // ws: overflow count (zeroed by K0)
    unsigned long long* __restrict__ ovf, // ws: (E,) overflow (cell<<32)|e
    int E)
{
    const int N = nn[0];
    const int tid    = blockIdx.x * blockDim.x + threadIdx.x;
    const int wave   = tid >> 6;
    const int lane   = threadIdx.x & 63;
    const int lg     = lane & 15;
    const int sub    = lane >> 4;
    const int nwaves = (gridDim.x * blockDim.x) >> 6;

    // W slice in registers: rows k = half*64 + lg*4 + c.
    float w[2][4][8];
#pragma unroll
    for (int half = 0; half < 2; ++half)
#pragma unroll
        for (int c = 0; c < 4; ++c) {
            const int k = half * 64 + lg * 4 + c;
#pragma unroll
            for (int h = 0; h < 8; ++h) w[half][c][h] = Wm[k * 8 + h];
        }
    float bh[8];
#pragma unroll
    for (int h = 0; h < 8; ++h) bh[h] = bv[h];

    const int nquads = (E + 3) >> 2;
    for (int q = wave; q < nquads; q += nwaves) {
        const int e = q * 4 + sub;
        const bool live = (e < E);

        int i = 0, j = 0;
        if (live) { i = ei[e]; j = ei[E + e]; }

        float acc[8];
#pragma unroll
        for (int h = 0; h < 8; ++h) acc[h] = 0.f;

        if (live) {
            const float4* row = (const float4*)(attr + (size_t)e * 128);
#pragma unroll
            for (int half = 0; half < 2; ++half) {
                const float4 v = row[half * 16 + lg];
#pragma unroll
                for (int h = 0; h < 8; ++h)
                    acc[h] += v.x * w[half][0][h] + v.y * w[half][1][h]
                            + v.z * w[half][2][h] + v.w * w[half][3][h];
            }
        }
        // 16-lane group tree reduce (xor masks 1,2,4,8 stay in-group on wave64).
#pragma unroll
        for (int d = 1; d < 16; d <<= 1)
#pragma unroll
            for (int h = 0; h < 8; ++h)
                acc[h] += __shfl_xor(acc[h], d, 64);

        if (live && lg < 8) {
            float v = acc[0] + bh[0];
#pragma unroll
            for (int h = 1; h < 8; ++h) {
                const float cand = acc[h] + bh[h];
                v = (lg == h) ? cand : v;
            }
            proj[(size_t)e * 8 + lg] = v;
        }
        if (live && lg == 0) {
            if (i >= 0 && i < N && j >= 0 && j < N) {
                const long cell = (long)i * N + j;
                const unsigned chunk = (unsigned)(cell >> 10);   // /CHUNK_CELLS
                const unsigned lc    = (unsigned)(cell & 1023u);
                const unsigned pos = atomicAdd(&counters[chunk], 1u);
                if (pos < BIN_CAP)
                    bins[(size_t)chunk * BIN_CAP + pos] = (lc << 20) | (unsigned)e;
                else {
                    const unsigned op = atomicAdd(ocnt, 1u);
                    ovf[op] = ((unsigned long long)cell << 32) | (unsigned)e;
                }
            }
        }
    }
}

// ---------------------------------------------------------- K4: fill + inject
__global__ __launch_bounds__(256) void efe_fill_inject_kernel(
    const unsigned* __restrict__ counters,
    const unsigned* __restrict__ bins,
    const float* __restrict__ proj,
    float* __restrict__ out)
{
    const unsigned chunk = blockIdx.x;
    const int t = threadIdx.x;

    // Header loads: counter + all 16 slots, issued as one parallel burst
    // (no dependent-load chain; garbage slots masked by cnt below).
    unsigned cnt = counters[chunk];
    const unsigned* mybins = bins + (size_t)chunk * BIN_CAP;
    unsigned rec[BIN_CAP];
#pragma unroll
    for (int r = 0; r < BIN_CAP; ++r) rec[r] = mybins[r];
    if (cnt > BIN_CAP) cnt = BIN_CAP;

    // Thread t owns float4 slots f = k*256 + t, k=0..7 (2048 float4 / chunk).
    f32x4 acc[8];
#pragma unroll
    for (int k = 0; k < 8; ++k) acc[k] = (f32x4)0.f;

#pragma unroll
    for (int r = 0; r < BIN_CAP; ++r) {
        if ((unsigned)r < cnt) {
            const int lc = (int)(rec[r] >> 20);
            const unsigned e = rec[r] & 0xFFFFFu;
            const int f0 = lc << 1, f1 = f0 | 1;
            if ((f0 & 255) == t) {
                const f32x4 p = *(const f32x4*)(proj + (size_t)e * 8);
                const int k = f0 >> 8;
#pragma unroll
                for (int kk = 0; kk < 8; ++kk)
                    if (kk == k) acc[kk] += p;
            }
            if ((f1 & 255) == t) {
                const f32x4 p = *(const f32x4*)(proj + (size_t)e * 8 + 4);
                const int k = f1 >> 8;
#pragma unroll
                for (int kk = 0; kk < 8; ++kk)
                    if (kk == k) acc[kk] += p;
            }
        }
    }

    // Nontemporal streaming stores: 8 x dwordx4 per thread, 1 KiB per wave
    // per instruction, no L2 write-allocate fetch of the output.
    f32x4* out4 = (f32x4*)out + (size_t)chunk * (CHUNK_CELLS * 8 / 4);
#pragma unroll
    for (int k = 0; k < 8; ++k)
        __builtin_nontemporal_store(acc[k], &out4[(size_t)k * 256 + t]);
}

// ------------------------------------------------------------ K5: overflow fix
__global__ __launch_bounds__(256) void efe_overflow_kernel(
    const unsigned* __restrict__ ocnt,
    const unsigned long long* __restrict__ ovf,
    const float* __restrict__ proj,
    float* __restrict__ out)
{
    const unsigned oc = *ocnt;                 // usually 0
    const int h = threadIdx.x & 7;
    const unsigned r0 = (blockIdx.x * blockDim.x + threadIdx.x) >> 3;
    const unsigned rstride = (gridDim.x * blockDim.x) >> 3;
    for (unsigned r = r0; r < oc; r += rstride) {
        const unsigned long long rec = ovf[r];
        const long cell = (long)(rec >> 32);
        const unsigned e = (unsigned)(rec & 0xFFFFFFFFu);
        atomicAdd(out + (size_t)cell * 8 + h, proj[(size_t)e * 8 + h]);
    }
}

// ------------------------------------------------------- fallback: atomic path
__global__ __launch_bounds__(256) void efe_scatter_kernel(
    const int* __restrict__ ei, const float* __restrict__ attr,
    const int* __restrict__ nn, const float* __restrict__ Wm,
    const float* __restrict__ bv, float* __restrict__ out, int E)
{
    const int N = nn[0];
    const int tid    = blockIdx.x * blockDim.x + threadIdx.x;
    const int wave   = tid >> 6;
    const int lane   = threadIdx.x & 63;
    const int lg     = lane & 15;
    const int sub    = lane >> 4;
    const int nwaves = (gridDim.x * blockDim.x) >> 6;

    float w[2][4][8];
#pragma unroll
    for (int half = 0; half < 2; ++half)
#pragma unroll
        for (int c = 0; c < 4; ++c) {
            const int k = half * 64 + lg * 4 + c;
#pragma unroll
            for (int h = 0; h < 8; ++h) w[half][c][h] = Wm[k * 8 + h];
        }
    float bh[8];
#pragma unroll
    for (int h = 0; h < 8; ++h) bh[h] = bv[h];

    const int nquads = (E + 3) >> 2;
    for (int q = wave; q < nquads; q += nwaves) {
        const int e = q * 4 + sub;
        const bool live = (e < E);
        int i = 0, j = 0;
        if (live) { i = ei[e]; j = ei[E + e]; }
        float acc[8];
#pragma unroll
        for (int h = 0; h < 8; ++h) acc[h] = 0.f;
        if (live) {
            const float4* row = (const float4*)(attr + (size_t)e * 128);
#pragma unroll
            for (int half = 0; half < 2; ++half) {
                const float4 v = row[half * 16 + lg];
#pragma unroll
                for (int h = 0; h < 8; ++h)
                    acc[h] += v.x * w[half][0][h] + v.y * w[half][1][h]
                            + v.z * w[half][2][h] + v.w * w[half][3][h];
            }
        }
#pragma unroll
        for (int d = 1; d < 16; d <<= 1)
#pragma unroll
            for (int h = 0; h < 8; ++h)
                acc[h] += __shfl_xor(acc[h], d, 64);
        if (live && lg < 8 && i >= 0 && i < N && j >= 0 && j < N) {
            float v = acc[0] + bh[0];
#pragma unroll
            for (int h = 1; h < 8; ++h) {
                const float cand = acc[h] + bh[h];
                v = (lg == h) ? cand : v;
            }
            atomicAdd(out + (((size_t)i * N + j) << 3) + lg, v);
        }
    }
}

extern "C" void kernel_launch(void* const* d_in, const int* in_sizes, int n_in,
                              void* d_out, int out_size, void* d_ws, size_t ws_size,
                              hipStream_t stream) {
    const int*   ei   = (const int*)d_in[0];
    const float* attr = (const float*)d_in[1];
    const int*   nn   = (const int*)d_in[2];
    const float* Wm   = (const float*)d_in[3];
    const float* bv   = (const float*)d_in[4];
    float*       out  = (float*)d_out;

    const int E = in_sizes[0] / 2;

    // Host-side geometry: out_size = N*N*8 (host doesn't see num_nodes' value).
    const long ncells = (long)out_size / 8;
    const long Nh = (long)(sqrt((double)ncells) + 0.5);
    const bool shape_ok = (Nh * Nh == ncells) && (ncells % CHUNK_CELLS == 0) &&
                          (E > 0) && (E <= (1 << 20));

    // ws layout (256B-aligned regions)
    const size_t nchunks = (size_t)(ncells / CHUNK_CELLS);
    const size_t o_cnt  = 0;                       // counters: nchunks u32
    const size_t o_ocnt = nchunks * 4;             // ocnt: 1 u32 (contiguous)
    const size_t o_ovf  = ((o_ocnt + 4 + 255) / 256) * 256;
    const size_t o_proj = ((o_ovf + (size_t)E * 8 + 255) / 256) * 256;
    const size_t o_bins = ((o_proj + (size_t)E * 32 + 255) / 256) * 256;
    const size_t need   = o_bins + nchunks * BIN_CAP * 4;

    if (shape_ok && ws_size >= need) {
        unsigned* counters = (unsigned*)((char*)d_ws + o_cnt);
        unsigned* ocnt     = (unsigned*)((char*)d_ws + o_ocnt);
        unsigned long long* ovf = (unsigned long long*)((char*)d_ws + o_ovf);
        float*    proj     = (float*)((char*)d_ws + o_proj);
        unsigned* bins     = (unsigned*)((char*)d_ws + o_bins);

        const int nzero = (int)nchunks + 1;        // counters + ocnt
        efe_zero_counters<<<(nzero + 255) / 256, 256, 0, stream>>>(counters, nzero);

        efe_proj_bin_kernel<<<2048, 256, 0, stream>>>(
            ei, attr, nn, Wm, bv, proj, counters, bins, ocnt, ovf, E);

        efe_fill_inject_kernel<<<(unsigned)nchunks, 256, 0, stream>>>(
            counters, bins, proj, out);

        efe_overflow_kernel<<<16, 256, 0, stream>>>(ocnt, ovf, proj, out);
    } else {
        // Fallback: memset node + atomic scatter.
        hipMemsetAsync(d_out, 0, (size_t)out_size * sizeof(float), stream);
        efe_scatter_kernel<<<2048, 256, 0, stream>>>(ei, attr, nn, Wm, bv, out, E);
    }
}

// Round 5
// 139.493 us; speedup vs baseline: 1.1346x; 1.0618x over previous
//
#include <hip/hip_runtime.h>
#include <math.h>

// EdgeFeatureEncoding: proj = edge_attr @ W + b (E x 8), scatter-add into
// dense (N, N, 8) bias at (i, j).
//
// Structure (this round): delegate the 512 MiB zero-fill to rocclr's memset
// (the only fill measured at 6.6-6.9 TB/s on this machine; our own streaming
// writes plateau at ~4.7 TB/s across two rounds), then inject ONLY the
// ~131K occupied cells with non-atomic merged stores:
//   memset(d_out)          ~81 us (proven in-graph, R1)
//   K0 zero counters/ocnt  ~2 us
//   K1 proj+bin            GEMM (16-lane groups, coalesced float4 reads,
//                          W in registers, shfl_xor reduce) + chunk binning.
//   K4' sparse inject      16-lane group per chunk: coalesced bin loads,
//                          in-register duplicate merge via __shfl(width=16),
//                          non-atomic 32 B stores (cells are zero post-memset).
//   K5 overflow            atomicAdd for records past BIN_CAP (Poisson tail).
// Fallback (odd shapes / small ws): memset + atomic scatter.

#define CHUNK_CELLS 1024   // cells per chunk (cell = 8 floats)
#define BIN_CAP     16     // slots per chunk; lambda ~= 8 here, tail -> K5

typedef float f32x4 __attribute__((ext_vector_type(4)));

// ------------------------------------------------------------- K0: zero state
__global__ __launch_bounds__(256) void efe_zero_counters(unsigned* __restrict__ p,
                                                         int n) {
    const int i = blockIdx.x * blockDim.x + threadIdx.x;
    if (i < n) p[i] = 0u;
}

// ---------------------------------------------------------------- K1: proj+bin
__global__ __launch_bounds__(256) void efe_proj_bin_kernel(
    const int* __restrict__ ei,      // (2, E): ei[e]=i, ei[E+e]=j
    const float* __restrict__ attr,  // (E, 128)
    const int* __restrict__ nn,      // num_nodes (device scalar)
    const float* __restrict__ Wm,    // (128, 8)
    const float* __restrict__ bv,    // (8,)
    float* __restrict__ proj,        // ws: (E, 8)
    unsigned* __restrict__ counters, // ws: (nchunks,) zeroed by K0
    unsigned* __restrict__ bins,     // ws: (nchunks, BIN_CAP) rec=(lc<<20)|e
    unsigned* __restrict__ ocnt,     // ws: overflow count (zeroed by K0)
    unsigned long long* __restrict__ ovf, // ws: (E,) overflow (cell<<32)|e
    int E)
{
    const int N = nn[0];
    const int tid    = blockIdx.x * blockDim.x + threadIdx.x;
    const int wave   = tid >> 6;
    const int lane   = threadIdx.x & 63;
    const int lg     = lane & 15;
    const int sub    = lane >> 4;
    const int nwaves = (gridDim.x * blockDim.x) >> 6;

    // W slice in registers: rows k = half*64 + lg*4 + c.
    float w[2][4][8];
#pragma unroll
    for (int half = 0; half < 2; ++half)
#pragma unroll
        for (int c = 0; c < 4; ++c) {
            const int k = half * 64 + lg * 4 + c;
#pragma unroll
            for (int h = 0; h < 8; ++h) w[half][c][h] = Wm[k * 8 + h];
        }
    float bh[8];
#pragma unroll
    for (int h = 0; h < 8; ++h) bh[h] = bv[h];

    const int nquads = (E + 3) >> 2;
    for (int q = wave; q < nquads; q += nwaves) {
        const int e = q * 4 + sub;
        const bool live = (e < E);

        int i = 0, j = 0;
        if (live) { i = ei[e]; j = ei[E + e]; }

        float acc[8];
#pragma unroll
        for (int h = 0; h < 8; ++h) acc[h] = 0.f;

        if (live) {
            const float4* row = (const float4*)(attr + (size_t)e * 128);
#pragma unroll
            for (int half = 0; half < 2; ++half) {
                const float4 v = row[half * 16 + lg];
#pragma unroll
                for (int h = 0; h < 8; ++h)
                    acc[h] += v.x * w[half][0][h] + v.y * w[half][1][h]
                            + v.z * w[half][2][h] + v.w * w[half][3][h];
            }
        }
        // 16-lane group tree reduce (xor masks 1,2,4,8 stay in-group on wave64).
#pragma unroll
        for (int d = 1; d < 16; d <<= 1)
#pragma unroll
            for (int h = 0; h < 8; ++h)
                acc[h] += __shfl_xor(acc[h], d, 64);

        if (live && lg < 8) {
            float v = acc[0] + bh[0];
#pragma unroll
            for (int h = 1; h < 8; ++h) {
                const float cand = acc[h] + bh[h];
                v = (lg == h) ? cand : v;
            }
            proj[(size_t)e * 8 + lg] = v;
        }
        if (live && lg == 0) {
            if (i >= 0 && i < N && j >= 0 && j < N) {
                const long cell = (long)i * N + j;
                const unsigned chunk = (unsigned)(cell >> 10);   // /CHUNK_CELLS
                const unsigned lc    = (unsigned)(cell & 1023u);
                const unsigned pos = atomicAdd(&counters[chunk], 1u);
                if (pos < BIN_CAP)
                    bins[(size_t)chunk * BIN_CAP + pos] = (lc << 20) | (unsigned)e;
                else {
                    const unsigned op = atomicAdd(ocnt, 1u);
                    ovf[op] = ((unsigned long long)cell << 32) | (unsigned)e;
                }
            }
        }
    }
}

// -------------------------------------------- K4': sparse merged inject (store)
// One 16-lane group per chunk; 16 groups per 256-thread block. Cells are zero
// after memset, so each merged per-cell sum is a plain store (no atomics).
__global__ __launch_bounds__(256) void efe_inject_kernel(
    const unsigned* __restrict__ counters,
    const unsigned* __restrict__ bins,
    const float* __restrict__ proj,
    float* __restrict__ out,
    unsigned nchunks)
{
    const unsigned chunk = blockIdx.x * 16 + (threadIdx.x >> 4);
    const int slot = threadIdx.x & 15;
    if (chunk >= nchunks) return;

    unsigned cnt = counters[chunk];
    if (cnt > BIN_CAP) cnt = BIN_CAP;

    // Coalesced: thread tid loads bins[chunkbase*16 + tid] across the block.
    const unsigned myrec = bins[(size_t)chunk * BIN_CAP + slot];
    const int mylc = (int)(myrec >> 20);
    const bool act = (slot < (int)cnt);

    f32x4 s0 = (f32x4)0.f, s1 = (f32x4)0.f;
    bool dup = false;

#pragma unroll
    for (int s = 0; s < BIN_CAP; ++s) {
        const unsigned rs = __shfl(myrec, s, 16);     // record s of my group
        const bool slive = (s < (int)cnt);
        const int slc = (int)(rs >> 20);
        const unsigned se = rs & 0xFFFFFu;
        if (slive && act && slc == mylc) {
            if (s < slot) dup = true;                 // earlier same-cell owner
            else {                                    // accumulate s's proj
                s0 += *(const f32x4*)(proj + (size_t)se * 8);
                s1 += *(const f32x4*)(proj + (size_t)se * 8 + 4);
            }
        }
    }

    if (act && !dup) {
        float* cell = out + (((size_t)chunk << 10) + mylc) * 8;
        *(f32x4*)cell = s0;
        *(f32x4*)(cell + 4) = s1;
    }
}

// ------------------------------------------------------------ K5: overflow fix
__global__ __launch_bounds__(256) void efe_overflow_kernel(
    const unsigned* __restrict__ ocnt,
    const unsigned long long* __restrict__ ovf,
    const float* __restrict__ proj,
    float* __restrict__ out)
{
    const unsigned oc = *ocnt;                 // ~0-100 records
    const int h = threadIdx.x & 7;
    const unsigned r0 = (blockIdx.x * blockDim.x + threadIdx.x) >> 3;
    const unsigned rstride = (gridDim.x * blockDim.x) >> 3;
    for (unsigned r = r0; r < oc; r += rstride) {
        const unsigned long long rec = ovf[r];
        const long cell = (long)(rec >> 32);
        const unsigned e = (unsigned)(rec & 0xFFFFFFFFu);
        atomicAdd(out + (size_t)cell * 8 + h, proj[(size_t)e * 8 + h]);
    }
}

// ------------------------------------------------------- fallback: atomic path
__global__ __launch_bounds__(256) void efe_scatter_kernel(
    const int* __restrict__ ei, const float* __restrict__ attr,
    const int* __restrict__ nn, const float* __restrict__ Wm,
    const float* __restrict__ bv, float* __restrict__ out, int E)
{
    const int N = nn[0];
    const int tid    = blockIdx.x * blockDim.x + threadIdx.x;
    const int wave   = tid >> 6;
    const int lane   = threadIdx.x & 63;
    const int lg     = lane & 15;
    const int sub    = lane >> 4;
    const int nwaves = (gridDim.x * blockDim.x) >> 6;

    float w[2][4][8];
#pragma unroll
    for (int half = 0; half < 2; ++half)
#pragma unroll
        for (int c = 0; c < 4; ++c) {
            const int k = half * 64 + lg * 4 + c;
#pragma unroll
            for (int h = 0; h < 8; ++h) w[half][c][h] = Wm[k * 8 + h];
        }
    float bh[8];
#pragma unroll
    for (int h = 0; h < 8; ++h) bh[h] = bv[h];

    const int nquads = (E + 3) >> 2;
    for (int q = wave; q < nquads; q += nwaves) {
        const int e = q * 4 + sub;
        const bool live = (e < E);
        int i = 0, j = 0;
        if (live) { i = ei[e]; j = ei[E + e]; }
        float acc[8];
#pragma unroll
        for (int h = 0; h < 8; ++h) acc[h] = 0.f;
        if (live) {
            const float4* row = (const float4*)(attr + (size_t)e * 128);
#pragma unroll
            for (int half = 0; half < 2; ++half) {
                const float4 v = row[half * 16 + lg];
#pragma unroll
                for (int h = 0; h < 8; ++h)
                    acc[h] += v.x * w[half][0][h] + v.y * w[half][1][h]
                            + v.z * w[half][2][h] + v.w * w[half][3][h];
            }
        }
#pragma unroll
        for (int d = 1; d < 16; d <<= 1)
#pragma unroll
            for (int h = 0; h < 8; ++h)
                acc[h] += __shfl_xor(acc[h], d, 64);
        if (live && lg < 8 && i >= 0 && i < N && j >= 0 && j < N) {
            float v = acc[0] + bh[0];
#pragma unroll
            for (int h = 1; h < 8; ++h) {
                const float cand = acc[h] + bh[h];
                v = (lg == h) ? cand : v;
            }
            atomicAdd(out + (((size_t)i * N + j) << 3) + lg, v);
        }
    }
}

extern "C" void kernel_launch(void* const* d_in, const int* in_sizes, int n_in,
                              void* d_out, int out_size, void* d_ws, size_t ws_size,
                              hipStream_t stream) {
    const int*   ei   = (const int*)d_in[0];
    const float* attr = (const float*)d_in[1];
    const int*   nn   = (const int*)d_in[2];
    const float* Wm   = (const float*)d_in[3];
    const float* bv   = (const float*)d_in[4];
    float*       out  = (float*)d_out;

    const int E = in_sizes[0] / 2;

    // Host-side geometry: out_size = N*N*8 (host doesn't see num_nodes' value).
    const long ncells = (long)out_size / 8;
    const long Nh = (long)(sqrt((double)ncells) + 0.5);
    const bool shape_ok = (Nh * Nh == ncells) && (ncells % CHUNK_CELLS == 0) &&
                          (E > 0) && (E <= (1 << 20));

    // ws layout (256B-aligned regions)
    const size_t nchunks = (size_t)(ncells / CHUNK_CELLS);
    const size_t o_cnt  = 0;                       // counters: nchunks u32
    const size_t o_ocnt = nchunks * 4;             // ocnt: 1 u32 (contiguous)
    const size_t o_ovf  = ((o_ocnt + 4 + 255) / 256) * 256;
    const size_t o_proj = ((o_ovf + (size_t)E * 8 + 255) / 256) * 256;
    const size_t o_bins = ((o_proj + (size_t)E * 32 + 255) / 256) * 256;
    const size_t need   = o_bins + nchunks * BIN_CAP * 4;

    if (shape_ok && ws_size >= need) {
        unsigned* counters = (unsigned*)((char*)d_ws + o_cnt);
        unsigned* ocnt     = (unsigned*)((char*)d_ws + o_ocnt);
        unsigned long long* ovf = (unsigned long long*)((char*)d_ws + o_ovf);
        float*    proj     = (float*)((char*)d_ws + o_proj);
        unsigned* bins     = (unsigned*)((char*)d_ws + o_bins);

        // The 512 MiB zero-fill: rocclr memset is the proven 6.6 TB/s path.
        hipMemsetAsync(d_out, 0, (size_t)out_size * sizeof(float), stream);

        const int nzero = (int)nchunks + 1;        // counters + ocnt
        efe_zero_counters<<<(nzero + 255) / 256, 256, 0, stream>>>(counters, nzero);

        // 1024 blocks: 4096 waves, 8 quad-iters/wave (W-preload amortized 2x
        // better than 2048 blocks, still 4 waves/SIMD for latency hiding).
        efe_proj_bin_kernel<<<1024, 256, 0, stream>>>(
            ei, attr, nn, Wm, bv, proj, counters, bins, ocnt, ovf, E);

        const unsigned injblocks = (unsigned)((nchunks + 15) / 16);
        efe_inject_kernel<<<injblocks, 256, 0, stream>>>(
            counters, bins, proj, out, (unsigned)nchunks);

        efe_overflow_kernel<<<16, 256, 0, stream>>>(ocnt, ovf, proj, out);
    } else {
        // Fallback: memset node + atomic scatter.
        hipMemsetAsync(d_out, 0, (size_t)out_size * sizeof(float), stream);
        efe_scatter_kernel<<<2048, 256, 0, stream>>>(ei, attr, nn, Wm, bv, out, E);
    }
}

// Round 6
// 121.061 us; speedup vs baseline: 1.3073x; 1.1522x over previous
//
#include <hip/hip_runtime.h>
#include <math.h>

// EdgeFeatureEncoding: proj = edge_attr @ W + b (E x 8), scatter-add into
// dense (N, N, 8) bias at (i, j).
//
// Structure (this round): FUSE the 512 MiB zero-fill with the proj+bin pass
// in ONE dispatch using role-split blocks (they touch disjoint buffers, so
// they can overlap; the graph would otherwise serialize them):
//   K0 zero counters/ocnt    ~2 us
//   KF fused fill||proj+bin  blocks bid%4==3 (512): proj GEMM + chunk binning;
//                            else (1536): nontemporal grid-stride fill of
//                            d_out. Fine interleave keeps a 3:1 resident mix
//                            per CU so fill writes and K1 reads overlap.
//   K4' sparse inject        16-lane group per chunk: merged per-cell sums,
//                            non-atomic 32 B stores onto zeroed cells.
//   K5 overflow              atomicAdd for records past BIN_CAP (rare tail).
// Fallback (odd shapes / small ws): memset + atomic scatter.

#define CHUNK_CELLS 1024   // cells per chunk (cell = 8 floats)
#define BIN_CAP     16     // slots per chunk; lambda ~= 8 here, tail -> K5

typedef float f32x4 __attribute__((ext_vector_type(4)));

// ------------------------------------------------------------- K0: zero state
__global__ __launch_bounds__(256) void efe_zero_counters(unsigned* __restrict__ p,
                                                         int n) {
    const int i = blockIdx.x * blockDim.x + threadIdx.x;
    if (i < n) p[i] = 0u;
}

// ----------------------------------------- KF: fused fill || proj+bin kernel
__global__ __launch_bounds__(256) void efe_fused_kernel(
    const int* __restrict__ ei,      // (2, E): ei[e]=i, ei[E+e]=j
    const float* __restrict__ attr,  // (E, 128)
    const int* __restrict__ nn,      // num_nodes (device scalar)
    const float* __restrict__ Wm,    // (128, 8)
    const float* __restrict__ bv,    // (8,)
    float* __restrict__ proj,        // ws: (E, 8)
    unsigned* __restrict__ counters, // ws: (nchunks,) zeroed by K0
    unsigned* __restrict__ bins,     // ws: (nchunks, BIN_CAP) rec=(lc<<20)|e
    unsigned* __restrict__ ocnt,     // ws: overflow count (zeroed by K0)
    unsigned long long* __restrict__ ovf, // ws: overflow (cell<<32)|e
    float* __restrict__ out,         // (N, N, 8) -> zero-filled by fill role
    long n4,                         // out_size/4 float4s
    int E)
{
    const int bid = blockIdx.x;
    const int role_k1 = ((bid & 3) == 3);

    if (!role_k1) {
        // ---- fill role: 3 of every 4 blocks, grid-stride nontemporal zeros.
        const int fid = (bid >> 2) * 3 + (bid & 3);        // 0..nfill-1
        const int nfill = ((int)gridDim.x >> 2) * 3;
        const long stride = (long)nfill * blockDim.x;
        const f32x4 z = (f32x4)0.f;
        f32x4* o4 = (f32x4*)out;
        for (long i = (long)fid * blockDim.x + threadIdx.x; i < n4; i += stride)
            __builtin_nontemporal_store(z, &o4[i]);
        return;
    }

    // ---- proj+bin role: 1 of every 4 blocks.
    const int kid = bid >> 2;                              // 0..nk1-1
    const int nk1 = (int)gridDim.x >> 2;
    const int N = nn[0];
    const int tid    = kid * blockDim.x + threadIdx.x;
    const int wave   = tid >> 6;
    const int lane   = threadIdx.x & 63;
    const int lg     = lane & 15;
    const int sub    = lane >> 4;
    const int nwaves = (nk1 * blockDim.x) >> 6;

    // W slice in registers: rows k = half*64 + lg*4 + c.
    float w[2][4][8];
#pragma unroll
    for (int half = 0; half < 2; ++half)
#pragma unroll
        for (int c = 0; c < 4; ++c) {
            const int k = half * 64 + lg * 4 + c;
#pragma unroll
            for (int h = 0; h < 8; ++h) w[half][c][h] = Wm[k * 8 + h];
        }
    float bh[8];
#pragma unroll
    for (int h = 0; h < 8; ++h) bh[h] = bv[h];

    const int nquads = (E + 3) >> 2;
    for (int q = wave; q < nquads; q += nwaves) {
        const int e = q * 4 + sub;
        const bool live = (e < E);

        int i = 0, j = 0;
        if (live) { i = ei[e]; j = ei[E + e]; }

        float acc[8];
#pragma unroll
        for (int h = 0; h < 8; ++h) acc[h] = 0.f;

        if (live) {
            const float4* row = (const float4*)(attr + (size_t)e * 128);
#pragma unroll
            for (int half = 0; half < 2; ++half) {
                const float4 v = row[half * 16 + lg];
#pragma unroll
                for (int h = 0; h < 8; ++h)
                    acc[h] += v.x * w[half][0][h] + v.y * w[half][1][h]
                            + v.z * w[half][2][h] + v.w * w[half][3][h];
            }
        }
        // 16-lane group tree reduce (xor masks 1,2,4,8 stay in-group on wave64).
#pragma unroll
        for (int d = 1; d < 16; d <<= 1)
#pragma unroll
            for (int h = 0; h < 8; ++h)
                acc[h] += __shfl_xor(acc[h], d, 64);

        if (live && lg < 8) {
            float v = acc[0] + bh[0];
#pragma unroll
            for (int h = 1; h < 8; ++h) {
                const float cand = acc[h] + bh[h];
                v = (lg == h) ? cand : v;
            }
            proj[(size_t)e * 8 + lg] = v;
        }
        if (live && lg == 0) {
            if (i >= 0 && i < N && j >= 0 && j < N) {
                const long cell = (long)i * N + j;
                const unsigned chunk = (unsigned)(cell >> 10);   // /CHUNK_CELLS
                const unsigned lc    = (unsigned)(cell & 1023u);
                const unsigned pos = atomicAdd(&counters[chunk], 1u);
                if (pos < BIN_CAP)
                    bins[(size_t)chunk * BIN_CAP + pos] = (lc << 20) | (unsigned)e;
                else {
                    const unsigned op = atomicAdd(ocnt, 1u);
                    ovf[op] = ((unsigned long long)cell << 32) | (unsigned)e;
                }
            }
        }
    }
}

// -------------------------------------------- K4': sparse merged inject (store)
// One 16-lane group per chunk; cells are zero post-fill, so merged per-cell
// sums are plain stores (no atomics).
__global__ __launch_bounds__(256) void efe_inject_kernel(
    const unsigned* __restrict__ counters,
    const unsigned* __restrict__ bins,
    const float* __restrict__ proj,
    float* __restrict__ out,
    unsigned nchunks)
{
    const unsigned chunk = blockIdx.x * 16 + (threadIdx.x >> 4);
    const int slot = threadIdx.x & 15;
    if (chunk >= nchunks) return;

    unsigned cnt = counters[chunk];
    if (cnt > BIN_CAP) cnt = BIN_CAP;

    const unsigned myrec = bins[(size_t)chunk * BIN_CAP + slot];
    const int mylc = (int)(myrec >> 20);
    const bool act = (slot < (int)cnt);

    f32x4 s0 = (f32x4)0.f, s1 = (f32x4)0.f;
    bool dup = false;

#pragma unroll
    for (int s = 0; s < BIN_CAP; ++s) {
        const unsigned rs = __shfl(myrec, s, 16);     // record s of my group
        const bool slive = (s < (int)cnt);
        const int slc = (int)(rs >> 20);
        const unsigned se = rs & 0xFFFFFu;
        if (slive && act && slc == mylc) {
            if (s < slot) dup = true;                 // earlier same-cell owner
            else {                                    // accumulate s's proj
                s0 += *(const f32x4*)(proj + (size_t)se * 8);
                s1 += *(const f32x4*)(proj + (size_t)se * 8 + 4);
            }
        }
    }

    if (act && !dup) {
        float* cell = out + (((size_t)chunk << 10) + mylc) * 8;
        *(f32x4*)cell = s0;
        *(f32x4*)(cell + 4) = s1;
    }
}

// ------------------------------------------------------------ K5: overflow fix
__global__ __launch_bounds__(256) void efe_overflow_kernel(
    const unsigned* __restrict__ ocnt,
    const unsigned long long* __restrict__ ovf,
    const float* __restrict__ proj,
    float* __restrict__ out)
{
    const unsigned oc = *ocnt;                 // ~0-100 records
    const int h = threadIdx.x & 7;
    const unsigned r0 = (blockIdx.x * blockDim.x + threadIdx.x) >> 3;
    const unsigned rstride = (gridDim.x * blockDim.x) >> 3;
    for (unsigned r = r0; r < oc; r += rstride) {
        const unsigned long long rec = ovf[r];
        const long cell = (long)(rec >> 32);
        const unsigned e = (unsigned)(rec & 0xFFFFFFFFu);
        atomicAdd(out + (size_t)cell * 8 + h, proj[(size_t)e * 8 + h]);
    }
}

// ------------------------------------------------------- fallback: atomic path
__global__ __launch_bounds__(256) void efe_scatter_kernel(
    const int* __restrict__ ei, const float* __restrict__ attr,
    const int* __restrict__ nn, const float* __restrict__ Wm,
    const float* __restrict__ bv, float* __restrict__ out, int E)
{
    const int N = nn[0];
    const int tid    = blockIdx.x * blockDim.x + threadIdx.x;
    const int wave   = tid >> 6;
    const int lane   = threadIdx.x & 63;
    const int lg     = lane & 15;
    const int sub    = lane >> 4;
    const int nwaves = (gridDim.x * blockDim.x) >> 6;

    float w[2][4][8];
#pragma unroll
    for (int half = 0; half < 2; ++half)
#pragma unroll
        for (int c = 0; c < 4; ++c) {
            const int k = half * 64 + lg * 4 + c;
#pragma unroll
            for (int h = 0; h < 8; ++h) w[half][c][h] = Wm[k * 8 + h];
        }
    float bh[8];
#pragma unroll
    for (int h = 0; h < 8; ++h) bh[h] = bv[h];

    const int nquads = (E + 3) >> 2;
    for (int q = wave; q < nquads; q += nwaves) {
        const int e = q * 4 + sub;
        const bool live = (e < E);
        int i = 0, j = 0;
        if (live) { i = ei[e]; j = ei[E + e]; }
        float acc[8];
#pragma unroll
        for (int h = 0; h < 8; ++h) acc[h] = 0.f;
        if (live) {
            const float4* row = (const float4*)(attr + (size_t)e * 128);
#pragma unroll
            for (int half = 0; half < 2; ++half) {
                const float4 v = row[half * 16 + lg];
#pragma unroll
                for (int h = 0; h < 8; ++h)
                    acc[h] += v.x * w[half][0][h] + v.y * w[half][1][h]
                            + v.z * w[half][2][h] + v.w * w[half][3][h];
            }
        }
#pragma unroll
        for (int d = 1; d < 16; d <<= 1)
#pragma unroll
            for (int h = 0; h < 8; ++h)
                acc[h] += __shfl_xor(acc[h], d, 64);
        if (live && lg < 8 && i >= 0 && i < N && j >= 0 && j < N) {
            float v = acc[0] + bh[0];
#pragma unroll
            for (int h = 1; h < 8; ++h) {
                const float cand = acc[h] + bh[h];
                v = (lg == h) ? cand : v;
            }
            atomicAdd(out + (((size_t)i * N + j) << 3) + lg, v);
        }
    }
}

extern "C" void kernel_launch(void* const* d_in, const int* in_sizes, int n_in,
                              void* d_out, int out_size, void* d_ws, size_t ws_size,
                              hipStream_t stream) {
    const int*   ei   = (const int*)d_in[0];
    const float* attr = (const float*)d_in[1];
    const int*   nn   = (const int*)d_in[2];
    const float* Wm   = (const float*)d_in[3];
    const float* bv   = (const float*)d_in[4];
    float*       out  = (float*)d_out;

    const int E = in_sizes[0] / 2;

    // Host-side geometry: out_size = N*N*8 (host doesn't see num_nodes' value).
    const long ncells = (long)out_size / 8;
    const long Nh = (long)(sqrt((double)ncells) + 0.5);
    const bool shape_ok = (Nh * Nh == ncells) && (ncells % CHUNK_CELLS == 0) &&
                          (E > 0) && (E <= (1 << 20));

    // ws layout (256B-aligned regions)
    const size_t nchunks = (size_t)(ncells / CHUNK_CELLS);
    const size_t o_cnt  = 0;                       // counters: nchunks u32
    const size_t o_ocnt = nchunks * 4;             // ocnt: 1 u32 (contiguous)
    const size_t o_ovf  = ((o_ocnt + 4 + 255) / 256) * 256;
    const size_t o_proj = ((o_ovf + (size_t)E * 8 + 255) / 256) * 256;
    const size_t o_bins = ((o_proj + (size_t)E * 32 + 255) / 256) * 256;
    const size_t need   = o_bins + nchunks * BIN_CAP * 4;

    if (shape_ok && ws_size >= need) {
        unsigned* counters = (unsigned*)((char*)d_ws + o_cnt);
        unsigned* ocnt     = (unsigned*)((char*)d_ws + o_ocnt);
        unsigned long long* ovf = (unsigned long long*)((char*)d_ws + o_ovf);
        float*    proj     = (float*)((char*)d_ws + o_proj);
        unsigned* bins     = (unsigned*)((char*)d_ws + o_bins);

        const int nzero = (int)nchunks + 1;        // counters + ocnt
        efe_zero_counters<<<(nzero + 255) / 256, 256, 0, stream>>>(counters, nzero);

        // Fused fill || proj+bin. 2048 blocks, fine 3:1 role interleave so the
        // resident mix per CU overlaps fill writes with proj reads/VALU.
        const long n4 = (long)out_size / 4;
        efe_fused_kernel<<<2048, 256, 0, stream>>>(
            ei, attr, nn, Wm, bv, proj, counters, bins, ocnt, ovf, out, n4, E);

        const unsigned injblocks = (unsigned)((nchunks + 15) / 16);
        efe_inject_kernel<<<injblocks, 256, 0, stream>>>(
            counters, bins, proj, out, (unsigned)nchunks);

        efe_overflow_kernel<<<16, 256, 0, stream>>>(ocnt, ovf, proj, out);
    } else {
        // Fallback: memset node + atomic scatter.
        hipMemsetAsync(d_out, 0, (size_t)out_size * sizeof(float), stream);
        efe_scatter_kernel<<<2048, 256, 0, stream>>>(ei, attr, nn, Wm, bv, out, E);
    }
}